// Round 5
// baseline (70.978 us; speedup 1.0000x reference)
//
#include <hip/hip_runtime.h>
#include <hip/hip_bf16.h>

// Problem constants (reference: B=128, K=2048, D=512, c=1.0)
#define B_SZ 128
#define K_SZ 2048
#define D_SZ 512
#define ROWP 520  // LDS row stride (bf16): 1040 B = 65 16B-granules, 65%8==1
                  // -> fragment ds_read_b128 perfectly bank-balanced

typedef __attribute__((ext_vector_type(8))) short short8;   // 8 bf16
typedef __attribute__((ext_vector_type(4))) float floatx4;  // MFMA acc

// Manual RNE fp32 -> bf16.
static __device__ inline unsigned short f2b(float f) {
  unsigned int u = __float_as_uint(f);
  return (unsigned short)((u + 0x7fffu + ((u >> 16) & 1u)) >> 16);
}

// ONE fused kernel, max-occupancy variant (R5).
// Block = 16b x 16k, grid = 8*128 = 1024 = 4 blocks/CU = 4 waves/SIMD.
// LDS ~25 KB: x tile (bf16) + MFMA partials + stats. p/a are NOT staged:
// streamed global(fp32) -> stats FMA -> bf16 pack -> MFMA B-fragment, with
// the 16 f4-loads spread across the K-loop so they overlap MFMA/VALU.
// Wave w owns d-quarter [128w, 128w+128): 4 K-steps x 2 MFMAs.
// blockIdx: kt = blk & 127 -> the 8 m-blocks of one k-tile differ by 128
// (== 0 mod 8) -> same XCD -> p/a L2-resident after first touch.
// Fragment layouts (m89/m91-verified):
//   A/B: row = lane&15, d = quad*8 + j (16B/lane; p/a row-major == B^T)
//   C/D: n = lane&15, m = quad*4 + reg
__global__ __launch_bounds__(256, 4) void fused_kernel(
    const float* __restrict__ x, const float* __restrict__ p,
    const float* __restrict__ a, float* __restrict__ out) {
  __shared__ unsigned short xs[16 * ROWP];  // 16640 B
  __shared__ float part_s[4 * 256];         // 4096 B  <x,p> partials
  __shared__ float part_a[4 * 256];         // 4096 B  <x,a> partials
  __shared__ float spp[4 * 16];             // sum p^2   per (wave, k-row)
  __shared__ float spa[4 * 16];             // sum p*a
  __shared__ float saa[4 * 16];             // sum a^2
  __shared__ float svv[16];                 // sum x^2   per b-row

  const int t = threadIdx.x;
  const int lane = t & 63;
  const int w = t >> 6;            // wave = d-quarter
  const int row16 = lane & 15;
  const int quad = lane >> 4;
  const int bm = (blockIdx.x >> 7) * 16;   // 8 m-tiles
  const int kn = (blockIdx.x & 127) * 16;  // 128 k-tiles
  const int d0 = w * 128;

  // ---- Phase 0: stage x (fp32 -> bf16 LDS) + vv stats.
  // Thread: row r = t>>4 (0..15), chunk s = t&15; 8 float4 each.
  {
    const int r = t >> 4, s = t & 15;
    const float4* src = (const float4*)(x + (size_t)(bm + r) * D_SZ);
    float vvp = 0.f;
#pragma unroll
    for (int i = 0; i < 8; ++i) {
      float4 v = src[s + i * 16];
      vvp += v.x * v.x + v.y * v.y + v.z * v.z + v.w * v.w;
      ushort4 c;
      c.x = f2b(v.x); c.y = f2b(v.y); c.z = f2b(v.z); c.w = f2b(v.w);
      *(ushort4*)&xs[r * ROWP + (s + i * 16) * 4] = c;
    }
    // Sum the 16 chunk-partials of each row (lanes differing in bits 0..3).
    vvp += __shfl_xor(vvp, 1, 64);
    vvp += __shfl_xor(vvp, 2, 64);
    vvp += __shfl_xor(vvp, 4, 64);
    vvp += __shfl_xor(vvp, 8, 64);
    if ((lane & 15) == 0) svv[t >> 4] = vvp;  // rows 4w + quad
  }

  // ---- Phase 1: stream p/a, fp32 stats, bf16 MFMA. 4 K-steps of 32.
  const float4* prow =
      (const float4*)(p + (size_t)(kn + row16) * D_SZ + d0 + quad * 8);
  const float4* arow =
      (const float4*)(a + (size_t)(kn + row16) * D_SZ + d0 + quad * 8);
  float pp = 0.f, pa = 0.f, aa = 0.f;
  floatx4 cs = {0.f, 0.f, 0.f, 0.f};
  floatx4 ca = {0.f, 0.f, 0.f, 0.f};
  __syncthreads();  // xs ready
#pragma unroll
  for (int step = 0; step < 4; ++step) {
    float4 p0 = prow[step * 8];
    float4 p1 = prow[step * 8 + 1];
    float4 a0 = arow[step * 8];
    float4 a1 = arow[step * 8 + 1];
    pp += p0.x * p0.x + p0.y * p0.y + p0.z * p0.z + p0.w * p0.w +
          p1.x * p1.x + p1.y * p1.y + p1.z * p1.z + p1.w * p1.w;
    aa += a0.x * a0.x + a0.y * a0.y + a0.z * a0.z + a0.w * a0.w +
          a1.x * a1.x + a1.y * a1.y + a1.z * a1.z + a1.w * a1.w;
    pa += p0.x * a0.x + p0.y * a0.y + p0.z * a0.z + p0.w * a0.w +
          p1.x * a1.x + p1.y * a1.y + p1.z * a1.z + p1.w * a1.w;
    short8 bp, bv;
    bp[0] = (short)f2b(p0.x); bp[1] = (short)f2b(p0.y);
    bp[2] = (short)f2b(p0.z); bp[3] = (short)f2b(p0.w);
    bp[4] = (short)f2b(p1.x); bp[5] = (short)f2b(p1.y);
    bp[6] = (short)f2b(p1.z); bp[7] = (short)f2b(p1.w);
    bv[0] = (short)f2b(a0.x); bv[1] = (short)f2b(a0.y);
    bv[2] = (short)f2b(a0.z); bv[3] = (short)f2b(a0.w);
    bv[4] = (short)f2b(a1.x); bv[5] = (short)f2b(a1.y);
    bv[6] = (short)f2b(a1.z); bv[7] = (short)f2b(a1.w);
    short8 af =
        *(const short8*)&xs[row16 * ROWP + d0 + step * 32 + quad * 8];
    cs = __builtin_amdgcn_mfma_f32_16x16x32_bf16(af, bp, cs, 0, 0, 0);
    ca = __builtin_amdgcn_mfma_f32_16x16x32_bf16(af, bv, ca, 0, 0, 0);
  }

  // Per-row stats for this d-quarter: sum over the 4 quads (lane bits 4,5).
  pp += __shfl_xor(pp, 16, 64); pp += __shfl_xor(pp, 32, 64);
  pa += __shfl_xor(pa, 16, 64); pa += __shfl_xor(pa, 32, 64);
  aa += __shfl_xor(aa, 16, 64); aa += __shfl_xor(aa, 32, 64);
  if (quad == 0) {
    spp[w * 16 + row16] = pp;
    spa[w * 16 + row16] = pa;
    saa[w * 16 + row16] = aa;
  }
  // MFMA partials to LDS.
  *(floatx4*)&part_s[t * 4] = cs;
  *(floatx4*)&part_a[t * 4] = ca;
  __syncthreads();

  // ---- Phase 2: epilogue, 1 output per thread (c = 1).
  const int m16 = t >> 4;  // local b
  const int n = t & 15;    // local k
  const int lsrc = ((m16 >> 2) << 4) | n;  // source lane quad*16 + n
  const int reg = m16 & 3;
  float sdot = 0.f, adot = 0.f;
  float uuk = 0.f, pak = 0.f, aak = 0.f;
#pragma unroll
  for (int ww = 0; ww < 4; ++ww) {
    sdot += part_s[(ww * 64 + lsrc) * 4 + reg];
    adot += part_a[(ww * 64 + lsrc) * 4 + reg];
    uuk += spp[ww * 16 + n];
    pak += spa[ww * 16 + n];
    aak += saa[ww * 16 + n];
  }
  const float vvb = svv[m16];
  const float nuak = -pak;
  const float ank = sqrtf(aak);
  const float beta = 1.f - uuk;            // 1 - c*||p||^2
  const float scale = (2.f / beta) * ank;  // lam_p * ||a||
  const float uv = -sdot;                  // <u,x> = -<p,x>
  const float alpha = 1.f + 2.f * uv + vvb;
  const float den = 1.f + 2.f * uv + uuk * vvb;
  const float inv = 1.f / den;
  const float wwn =
      (alpha * alpha * uuk + 2.f * alpha * beta * uv + beta * beta * vvb) *
      inv * inv;
  const float wa = (alpha * nuak + beta * adot) * inv;
  const float z = 2.f * wa / (ank * (1.f - wwn));
  out[(size_t)(bm + m16) * K_SZ + (kn + n)] = scale * asinhf(z);
}

extern "C" void kernel_launch(void* const* d_in, const int* in_sizes, int n_in,
                              void* d_out, int out_size, void* d_ws, size_t ws_size,
                              hipStream_t stream) {
  const float* x = (const float*)d_in[0];  // inp [B,D]
  const float* p = (const float*)d_in[1];  // p   [K,D]
  const float* a = (const float*)d_in[2];  // a   [K,D]
  float* out = (float*)d_out;              // [B,K] fp32
  (void)d_ws; (void)ws_size;               // no workspace needed

  fused_kernel<<<(B_SZ / 16) * (K_SZ / 16), 256, 0, stream>>>(x, p, a, out);
}